// Round 21
// baseline (141.687 us; speedup 1.0000x reference)
//
#include <hip/hip_runtime.h>

#define D8      8
#define LPATH   2048
#define NBATCH  64
#define NSTEPS  2047         // L-1 increments
#define CSTEPS  64           // increments per chunk (last chunk: 63)
#define SIGLEN  4680         // 8 + 64 + 512 + 4096
#define OFF2    8
#define OFF3    72
#define A3P     72           // padded A3 row pitch in LDS sig
#define SOFF4   (OFF3 + 8 * A3P)        // 648
#define P4      68           // padded A4 row pitch in LDS sig
#define SIGP    (SOFF4 + 64 * P4)       // 5000 floats = 20 KB
#define OFF4    584          // canonical (global) A4 offset
#define ZPITCH  68           // transposed-z row pitch (floats)
#define APITCH  40           // staged row pitch (shorts) = 80 B
#define BROWS   80           // B rows: 64 kl + 8 z-rows + 8 zero-rows

typedef float  f32x4 __attribute__((ext_vector_type(4)));
typedef short  s16x8 __attribute__((ext_vector_type(8)));

__device__ __forceinline__ void load8(const float* __restrict__ p, float* v) {
    float4 a = ((const float4*)p)[0];
    float4 b = ((const float4*)p)[1];
    v[0]=a.x; v[1]=a.y; v[2]=a.z; v[3]=a.w;
    v[4]=b.x; v[5]=b.y; v[6]=b.z; v[7]=b.w;
}
__device__ __forceinline__ void store8(float* __restrict__ p, const float* v) {
    ((float4*)p)[0] = make_float4(v[0],v[1],v[2],v[3]);
    ((float4*)p)[1] = make_float4(v[4],v[5],v[6],v[7]);
}
__device__ __forceinline__ unsigned int f2bf(float f) {   // RNE f32->bf16 bits (r14-proven)
    unsigned int u = __builtin_bit_cast(unsigned int, f);
    u += 0x7FFFu + ((u >> 16) & 1u);
    return u >> 16;
}

__device__ __forceinline__ void one_step(float Zi, float Zj,
                                         float& A2, float& a1i, float& Wl,
                                         float& c3o, float& c4o, float& h3o, float& h4o) {
    const float p  = Zi * Zj;
    const float uq = a1i * Zj;
    c4o = fmaf(uq, 1.f/6.f, fmaf(p, 1.f/24.f, A2 * 0.5f));
    c3o = fmaf(uq, 0.5f,    fmaf(p, 1.f/6.f,  A2));
    Wl -= Zj;
    h3o = Zi * Wl;
    h4o = p;
    A2 = A2 + fmaf(p, 0.5f, uq);
    a1i += Zi;
}

// Chen combine of register running-sig (k-row w) with a padded-layout LDS sig.
// Register-light (~40 live): used by BOTH the in-block fold and the batch tail.
__device__ __forceinline__ void sb_combine(const float* __restrict__ SB,
                                           int w, int lane, int i, int j,
                                           float (&FA4)[8], float& fa3, float (&FA1)[8],
                                           float& FA2, float& fa1i) {
    float B1[8]; load8(SB, B1);
    const float b1i = SB[i];
    const float b1j = SB[j];
    const float b2t = SB[OFF2 + lane];
    const float b1k = SB[w];
    const float b3k = SB[OFF3 + i * A3P + j * 8 + w];
    const float b2jk = SB[OFF2 + j * 8 + w];
    float b4r[8], b2r[8], b3r[8];
    load8(SB + SOFF4 + lane * P4 + w * 8, b4r);
    load8(SB + OFF2 + w * 8,              b2r);
    load8(SB + OFF3 + j * A3P + w * 8,    b3r);
#pragma unroll
    for (int l = 0; l < 8; ++l) {
        float v = FA4[l] + b4r[l];
        v = fmaf(fa3,  B1[l], v);
        v = fmaf(FA2,  b2r[l], v);
        FA4[l] = fmaf(fa1i, b3r[l], v);
    }
    fa3 = fmaf(fa1i, b2jk, fmaf(FA2, b1k, fa3 + b3k));
    FA2 = FA2 + fmaf(fa1i, b1j, b2t);
#pragma unroll
    for (int m = 0; m < 8; ++m) FA1[m] += B1[m];
    fa1i += b1i;
}

__device__ __forceinline__ void sb_init(const float* __restrict__ SB,
                                        int w, int lane, int i, int j,
                                        float (&FA4)[8], float& fa3, float (&FA1)[8],
                                        float& FA2, float& fa1i) {
    load8(SB, FA1);
    fa1i = SB[i];
    FA2  = SB[OFF2 + lane];
    fa3  = SB[OFF3 + i * A3P + j * 8 + w];
    load8(SB + SOFF4 + lane * P4 + w * 8, FA4);
}

// ==================== Single kernel: chunk sigs (MFMA) + fold-8 + LDS-staged batch tail ====================
__global__ __launch_bounds__(512) void sig_group_kernel(const float* __restrict__ path,
                                                        float* __restrict__ gsigs,
                                                        float* __restrict__ out,
                                                        int* __restrict__ cnt) {
    __shared__ __align__(16) float          zt[8][8 * ZPITCH];
    __shared__ __align__(16) unsigned short Al[8][64 * APITCH];
    __shared__ __align__(16) unsigned short Bl[8][BROWS * APITCH];
    __shared__ __align__(16) float          SB[SIGP];
    __shared__ int lastflag;

    const int tid  = threadIdx.x;
    const int w    = tid >> 6;
    const int lane = tid & 63;
    const int G    = blockIdx.x & 3;
    const int b    = blockIdx.x >> 2;
    const int c    = G * 8 + w;
    const int t0   = c * CSTEPS;
    const int t1   = (t0 + CSTEPS < NSTEPS) ? (t0 + CSTEPS) : NSTEPS;
    const int n    = t1 - t0;
    const int i    = lane >> 3;
    const int j    = lane & 7;
    const float* __restrict__ pb = path + (size_t)b * LPATH * D8;

    float* __restrict__ zw = &zt[w][0];
    unsigned short* __restrict__ Aw = &Al[w][0];
    unsigned short* __restrict__ Bw = &Bl[w][0];

    // ---- prologue: transposed z + zero B rows 64..79 ----
    {
        float z8[8];
        if (lane < n) {
            const float* s0 = pb + (size_t)(t0 + lane) * D8;
            float a0[8], a1v[8];
            load8(s0, a0); load8(s0 + D8, a1v);
#pragma unroll
            for (int m = 0; m < 8; ++m) z8[m] = a1v[m] - a0[m];
        } else {
#pragma unroll
            for (int m = 0; m < 8; ++m) z8[m] = 0.f;
        }
#pragma unroll
        for (int m = 0; m < 8; ++m) zw[m * ZPITCH + lane] = z8[m];

        const uint4 zz = make_uint4(0u, 0u, 0u, 0u);
        *(uint4*)(Bw + 64 * APITCH + lane * 8) = zz;
        if (lane < 16) *(uint4*)(Bw + 64 * APITCH + 512 + lane * 8) = zz;
    }

    const float Tj = pb[(size_t)t1 * D8 + j] - pb[(size_t)t0 * D8 + j];

    float A2 = 0.f, a1i = 0.f, Wl = Tj;
    f32x4 acc[4][5];
#pragma unroll
    for (int rt = 0; rt < 4; ++rt)
#pragma unroll
        for (int ct = 0; ct < 5; ++ct)
            acc[rt][ct] = (f32x4){0.f, 0.f, 0.f, 0.f};

    for (int pass = 0; pass < 4; ++pass) {
        const int p16 = pass * 16;
#pragma unroll
        for (int bt = 0; bt < 2; ++bt) {
            const int sb8 = p16 + bt * 8;
            f32x4 zia = *(const f32x4*)(zw + i * ZPITCH + sb8);
            f32x4 zib = *(const f32x4*)(zw + i * ZPITCH + sb8 + 4);
            f32x4 zja = *(const f32x4*)(zw + j * ZPITCH + sb8);
            f32x4 zjb = *(const f32x4*)(zw + j * ZPITCH + sb8 + 4);

            unsigned int c3pk[4], c4pk[4], h3pk[4], h4pk[4];
#pragma unroll
            for (int t = 0; t < 4; ++t) {
                const float Zi0 = (2*t   < 4) ? zia[(2*t)   & 3] : zib[(2*t)   & 3];
                const float Zi1 = (2*t+1 < 4) ? zia[(2*t+1) & 3] : zib[(2*t+1) & 3];
                const float Zj0 = (2*t   < 4) ? zja[(2*t)   & 3] : zjb[(2*t)   & 3];
                const float Zj1 = (2*t+1 < 4) ? zja[(2*t+1) & 3] : zjb[(2*t+1) & 3];
                float c3a, c4a, h3a, h4a, c3b, c4b, h3b, h4b;
                one_step(Zi0, Zj0, A2, a1i, Wl, c3a, c4a, h3a, h4a);
                one_step(Zi1, Zj1, A2, a1i, Wl, c3b, c4b, h3b, h4b);
                c3pk[t] = f2bf(c3a) | (f2bf(c3b) << 16);
                c4pk[t] = f2bf(c4a) | (f2bf(c4b) << 16);
                h3pk[t] = f2bf(h3a) | (f2bf(h3b) << 16);
                h4pk[t] = f2bf(h4a) | (f2bf(h4b) << 16);
            }
            *(uint4*)(Aw + lane * APITCH + bt * 8)      = make_uint4(c3pk[0], c3pk[1], c3pk[2], c3pk[3]);
            *(uint4*)(Aw + lane * APITCH + 16 + bt * 8) = make_uint4(c4pk[0], c4pk[1], c4pk[2], c4pk[3]);
            *(uint4*)(Bw + lane * APITCH + bt * 8)      = make_uint4(h3pk[0], h3pk[1], h3pk[2], h3pk[3]);
            *(uint4*)(Bw + lane * APITCH + 16 + bt * 8) = make_uint4(h4pk[0], h4pk[1], h4pk[2], h4pk[3]);
            if (j == 0) {   // z-rows for the A3 output tile (c3 K-half; c4 half stays 0)
                const unsigned int z0 = f2bf(zia[0]) | (f2bf(zia[1]) << 16);
                const unsigned int z1 = f2bf(zia[2]) | (f2bf(zia[3]) << 16);
                const unsigned int z2 = f2bf(zib[0]) | (f2bf(zib[1]) << 16);
                const unsigned int z3 = f2bf(zib[2]) | (f2bf(zib[3]) << 16);
                *(uint4*)(Bw + (64 + i) * APITCH + bt * 8) = make_uint4(z0, z1, z2, z3);
            }
        }
        s16x8 af[4], bfr[5];
#pragma unroll
        for (int rt = 0; rt < 4; ++rt)
            af[rt] = *(const s16x8*)(Aw + (rt * 16 + (lane & 15)) * APITCH + (lane >> 4) * 8);
#pragma unroll
        for (int ct = 0; ct < 5; ++ct)
            bfr[ct] = *(const s16x8*)(Bw + (ct * 16 + (lane & 15)) * APITCH + (lane >> 4) * 8);
#pragma unroll
        for (int rt = 0; rt < 4; ++rt)
#pragma unroll
            for (int ct = 0; ct < 5; ++ct)
                acc[rt][ct] = __builtin_amdgcn_mfma_f32_16x16x32_bf16(af[rt], bfr[ct], acc[rt][ct], 0, 0, 0);
    }

    // ==================== in-block fold-8 (wave w owns k-row w) ====================
    const int r0 = (lane >> 4) * 4;    // C/D: row = (lane>>4)*4 + reg, col = lane&15
    const int cl = lane & 15;
    float FA4[8], fa3, FA1[8], FA2, fa1i;

    __syncthreads();
    for (int s = 0; s < 8; ++s) {
        if (w == s) {                  // dump my chunk sig into SB (padded layout)
            if ((lane & 7) == 0) SB[lane >> 3] = a1i;          // A1[i]
            SB[OFF2 + lane] = A2;
            if (cl < 8) {              // A3 from GEMM tile ct=4
#pragma unroll
                for (int rt = 0; rt < 4; ++rt)
#pragma unroll
                    for (int reg = 0; reg < 4; ++reg) {
                        const int row = rt * 16 + r0 + reg;
                        SB[OFF3 + (row >> 3) * A3P + (row & 7) * 8 + cl] = acc[rt][4][reg];
                    }
            }
#pragma unroll
            for (int rt = 0; rt < 4; ++rt)
#pragma unroll
                for (int ct = 0; ct < 4; ++ct)
#pragma unroll
                    for (int reg = 0; reg < 4; ++reg)
                        SB[SOFF4 + (rt * 16 + r0 + reg) * P4 + ct * 16 + cl] = acc[rt][ct][reg];
        }
        __syncthreads();
        if (s == 0) sb_init(SB, w, lane, i, j, FA4, fa3, FA1, FA2, fa1i);
        else        sb_combine(SB, w, lane, i, j, FA4, fa3, FA1, FA2, fa1i);
        __syncthreads();
    }

    // ---- write group sig (canonical layout, global) ----
    {
        float* __restrict__ o = gsigs + (size_t)blockIdx.x * SIGLEN;
        if (w == 0) {
            if (lane < 8) o[lane] = FA1[lane];
            o[OFF2 + lane] = FA2;
        }
        o[OFF3 + lane * 8 + w] = fa3;
        store8(o + OFF4 + lane * 64 + w * 8, FA4);
    }

    // ==================== atomic tail: last block per batch folds the 4 group sigs ====================
    // Register-light: stages each group sig through SB (padded layout) and reuses sb_combine.
    __threadfence();                       // release my gsig stores (device scope)
    __syncthreads();
    if (tid == 0)
        lastflag = (atomicAdd(&cnt[b], 1) == 3);
    __syncthreads();
    if (lastflag) {
        __threadfence();                   // acquire other blocks' gsig stores
        for (int s = 0; s < 4; ++s) {
            const float* __restrict__ g = gsigs + (size_t)(b * 4 + s) * SIGLEN;
            // cooperative copy canonical -> padded SB (512 threads)
            if (tid < 72) SB[tid] = g[tid];
            {
                const int ij = tid >> 3, k = tid & 7;                  // A3: 512 elems
                SB[OFF3 + (ij >> 3) * A3P + (ij & 7) * 8 + k] = g[OFF3 + tid];
            }
#pragma unroll
            for (int r = 0; r < 8; ++r) {                              // A4: 4096 elems
                const int e = r * 512 + tid;
                SB[SOFF4 + (e >> 6) * P4 + (e & 63)] = g[OFF4 + e];
            }
            __syncthreads();
            if (s == 0) sb_init(SB, w, lane, i, j, FA4, fa3, FA1, FA2, fa1i);
            else        sb_combine(SB, w, lane, i, j, FA4, fa3, FA1, FA2, fa1i);
            __syncthreads();
        }
        float* __restrict__ o = out + (size_t)b * SIGLEN;
        if (w == 0) {
            if (lane < 8) o[lane] = FA1[lane];
            o[OFF2 + lane] = FA2;
        }
        o[OFF3 + lane * 8 + w] = fa3;
        store8(o + OFF4 + lane * 64 + w * 8, FA4);
    }
}

extern "C" void kernel_launch(void* const* d_in, const int* in_sizes, int n_in,
                              void* d_out, int out_size, void* d_ws, size_t ws_size,
                              hipStream_t stream) {
    const float* path = (const float*)d_in[0];
    float* out   = (float*)d_out;
    float* gsigs = (float*)d_ws;                               // 256 * 4680 f32 = 4.79 MB
    int*   cnt   = (int*)((char*)d_ws + (size_t)NBATCH * 4 * SIGLEN * sizeof(float));

    (void)hipMemsetAsync(cnt, 0, NBATCH * sizeof(int), stream);  // replay-safe counters
    sig_group_kernel<<<NBATCH * 4, 512, 0, stream>>>(path, gsigs, out, cnt);
}

// Round 22
// 50.202 us; speedup vs baseline: 2.8223x; 2.8223x over previous
//
#include <hip/hip_runtime.h>

#define D8      8
#define LPATH   2048
#define NBATCH  64
#define NSTEPS  2047         // L-1 increments
#define CSTEPS  64           // increments per chunk (last chunk: 63)
#define SIGLEN  4680         // 8 + 64 + 512 + 4096
#define OFF2    8
#define OFF3    72
#define A3P     72           // padded A3 row pitch in LDS sig
#define SOFF4   (OFF3 + 8 * A3P)        // 648
#define P4      68           // padded A4 row pitch in LDS sig
#define SIGP    (SOFF4 + 64 * P4)       // 5000 floats = 20 KB
#define OFF4    584          // canonical (global) A4 offset
#define ZPITCH  68           // transposed-z row pitch (floats)
#define APITCH  40           // staged row pitch (shorts) = 80 B
#define BROWS   80           // B rows: 64 kl + 8 z-rows + 8 zero-rows

// smem byte layout (fold buffer SB aliases the dead A/B staging region):
#define A_OFF   0                        // 2 chunks * 64*APITCH*2B  = 10240
#define B_OFF   10240                    // 2 chunks * 80*APITCH*2B  = 12800
#define Z_OFF   23040                    // 2 chunks * 8*ZPITCH*4B   = 4352
#define SMEM_BYTES 27392                 // SB = floats [0, 20000) < Z_OFF

typedef float  f32x4 __attribute__((ext_vector_type(4)));
typedef short  s16x8 __attribute__((ext_vector_type(8)));

__device__ __forceinline__ void load8(const float* __restrict__ p, float* v) {
    float4 a = ((const float4*)p)[0];
    float4 b = ((const float4*)p)[1];
    v[0]=a.x; v[1]=a.y; v[2]=a.z; v[3]=a.w;
    v[4]=b.x; v[5]=b.y; v[6]=b.z; v[7]=b.w;
}
__device__ __forceinline__ void store8(float* __restrict__ p, const float* v) {
    ((float4*)p)[0] = make_float4(v[0],v[1],v[2],v[3]);
    ((float4*)p)[1] = make_float4(v[4],v[5],v[6],v[7]);
}
__device__ __forceinline__ unsigned int f2bf(float f) {   // RNE f32->bf16 bits (proven)
    unsigned int u = __builtin_bit_cast(unsigned int, f);
    u += 0x7FFFu + ((u >> 16) & 1u);
    return u >> 16;
}

__device__ __forceinline__ void one_step(float Zi, float Zj,
                                         float& A2, float& a1i, float& Wl,
                                         float& c3o, float& c4o, float& h3o, float& h4o) {
    const float p  = Zi * Zj;
    const float uq = a1i * Zj;
    c4o = fmaf(uq, 1.f/6.f, fmaf(p, 1.f/24.f, A2 * 0.5f));
    c3o = fmaf(uq, 0.5f,    fmaf(p, 1.f/6.f,  A2));
    Wl -= Zj;
    h3o = Zi * Wl;
    h4o = p;
    A2 = A2 + fmaf(p, 0.5f, uq);
    a1i += Zi;
}

// ==================== Phase 1: wave-pair chunks (MFMA) + in-block fold-2 ====================
// 1024 blocks x 256 threads (4 waves). Wave pair {2c,2c+1} computes one chunk:
// wave h owns output rows 32h..32h+31 (acc[2][5] = 40 regs). Fold-2 -> group sig.
__global__ __launch_bounds__(256) void sig_pair_kernel(const float* __restrict__ path,
                                                       float* __restrict__ gsigs) {
    __shared__ __align__(16) unsigned char smem[SMEM_BYTES];

    const int tid  = threadIdx.x;
    const int w    = tid >> 6;            // 0..3
    const int cw   = w >> 1;              // chunk-in-block 0..1
    const int h    = w & 1;               // row-half of the pair
    const int lane = tid & 63;
    const int g    = blockIdx.x & 15;     // group within batch
    const int b    = blockIdx.x >> 4;     // batch
    const int c    = g * 2 + cw;          // chunk within batch (0..31)
    const int t0   = c * CSTEPS;
    const int t1   = (t0 + CSTEPS < NSTEPS) ? (t0 + CSTEPS) : NSTEPS;
    const int n    = t1 - t0;             // 64 or 63
    const int i    = lane >> 3;
    const int j    = lane & 7;
    const float* __restrict__ pb = path + (size_t)b * LPATH * D8;

    unsigned short* __restrict__ Aw = (unsigned short*)(smem + A_OFF) + cw * (64 * APITCH);
    unsigned short* __restrict__ Bw = (unsigned short*)(smem + B_OFF) + cw * (BROWS * APITCH);
    float* __restrict__ zw = (float*)(smem + Z_OFF) + cw * (8 * ZPITCH);
    float* __restrict__ SB = (float*)smem;          // fold buffer, aliases A/B staging

    // ---- prologue: h=0 writes transposed z; h=1 zeroes B rows 64..79 ----
    if (h == 0) {
        float z8[8];
        if (lane < n) {
            const float* s0 = pb + (size_t)(t0 + lane) * D8;
            float a0[8], a1v[8];
            load8(s0, a0); load8(s0 + D8, a1v);
#pragma unroll
            for (int m = 0; m < 8; ++m) z8[m] = a1v[m] - a0[m];
        } else {
#pragma unroll
            for (int m = 0; m < 8; ++m) z8[m] = 0.f;
        }
#pragma unroll
        for (int m = 0; m < 8; ++m) zw[m * ZPITCH + lane] = z8[m];
    } else {
        const uint4 zz = make_uint4(0u, 0u, 0u, 0u);
        *(uint4*)(Bw + 64 * APITCH + lane * 8) = zz;                 // shorts [2560,3072)
        if (lane < 16) *(uint4*)(Bw + 64 * APITCH + 512 + lane * 8) = zz;  // [3072,3200)
    }
    __syncthreads();

    const float Tj = pb[(size_t)t1 * D8 + j] - pb[(size_t)t0 * D8 + j];

    float A2 = 0.f, a1i = 0.f, Wl = Tj;
    f32x4 acc[2][5];
#pragma unroll
    for (int rt = 0; rt < 2; ++rt)
#pragma unroll
        for (int ct = 0; ct < 5; ++ct)
            acc[rt][ct] = (f32x4){0.f, 0.f, 0.f, 0.f};

    for (int pass = 0; pass < 4; ++pass) {
        const int p16 = pass * 16;
#pragma unroll
        for (int bt = 0; bt < 2; ++bt) {
            const int sb8 = p16 + bt * 8;
            f32x4 zia = *(const f32x4*)(zw + i * ZPITCH + sb8);
            f32x4 zib = *(const f32x4*)(zw + i * ZPITCH + sb8 + 4);
            f32x4 zja = *(const f32x4*)(zw + j * ZPITCH + sb8);
            f32x4 zjb = *(const f32x4*)(zw + j * ZPITCH + sb8 + 4);

            unsigned int c3pk[4], c4pk[4], h3pk[4], h4pk[4];
#pragma unroll
            for (int t = 0; t < 4; ++t) {
                const float Zi0 = (2*t   < 4) ? zia[(2*t)   & 3] : zib[(2*t)   & 3];
                const float Zi1 = (2*t+1 < 4) ? zia[(2*t+1) & 3] : zib[(2*t+1) & 3];
                const float Zj0 = (2*t   < 4) ? zja[(2*t)   & 3] : zjb[(2*t)   & 3];
                const float Zj1 = (2*t+1 < 4) ? zja[(2*t+1) & 3] : zjb[(2*t+1) & 3];
                float c3a, c4a, h3a, h4a, c3b, c4b, h3b, h4b;
                one_step(Zi0, Zj0, A2, a1i, Wl, c3a, c4a, h3a, h4a);
                one_step(Zi1, Zj1, A2, a1i, Wl, c3b, c4b, h3b, h4b);
                c3pk[t] = f2bf(c3a) | (f2bf(c3b) << 16);
                c4pk[t] = f2bf(c4a) | (f2bf(c4b) << 16);
                h3pk[t] = f2bf(h3a) | (f2bf(h3b) << 16);
                h4pk[t] = f2bf(h4a) | (f2bf(h4b) << 16);
            }
            if (h == 0) {     // stage A tile (c3 | c4)
                *(uint4*)(Aw + lane * APITCH + bt * 8)      = make_uint4(c3pk[0], c3pk[1], c3pk[2], c3pk[3]);
                *(uint4*)(Aw + lane * APITCH + 16 + bt * 8) = make_uint4(c4pk[0], c4pk[1], c4pk[2], c4pk[3]);
            } else {          // stage B tile (h3 | h4) + z-rows for the A3 output tile
                *(uint4*)(Bw + lane * APITCH + bt * 8)      = make_uint4(h3pk[0], h3pk[1], h3pk[2], h3pk[3]);
                *(uint4*)(Bw + lane * APITCH + 16 + bt * 8) = make_uint4(h4pk[0], h4pk[1], h4pk[2], h4pk[3]);
                if (j == 0) {
                    const unsigned int z0 = f2bf(zia[0]) | (f2bf(zia[1]) << 16);
                    const unsigned int z1 = f2bf(zia[2]) | (f2bf(zia[3]) << 16);
                    const unsigned int z2 = f2bf(zib[0]) | (f2bf(zib[1]) << 16);
                    const unsigned int z3 = f2bf(zib[2]) | (f2bf(zib[3]) << 16);
                    *(uint4*)(Bw + (64 + i) * APITCH + bt * 8) = make_uint4(z0, z1, z2, z3);
                }
            }
        }
        __syncthreads();      // staging visible to both waves of the pair
        s16x8 af[2], bfr[5];
#pragma unroll
        for (int rt = 0; rt < 2; ++rt)
            af[rt] = *(const s16x8*)(Aw + (((2*h + rt) * 16) + (lane & 15)) * APITCH + (lane >> 4) * 8);
#pragma unroll
        for (int ct = 0; ct < 5; ++ct)
            bfr[ct] = *(const s16x8*)(Bw + (ct * 16 + (lane & 15)) * APITCH + (lane >> 4) * 8);
#pragma unroll
        for (int rt = 0; rt < 2; ++rt)
#pragma unroll
            for (int ct = 0; ct < 5; ++ct)
                acc[rt][ct] = __builtin_amdgcn_mfma_f32_16x16x32_bf16(af[rt], bfr[ct], acc[rt][ct], 0, 0, 0);
        __syncthreads();      // fragment reads done before next pass overwrites
    }

    // ==================== in-block fold-2 (wave w owns k-rows {2w, 2w+1}) ====================
    const int r0 = (lane >> 4) * 4;    // C/D: row = (lane>>4)*4 + reg, col = lane&15
    const int cl = lane & 15;
    const int k0 = 2 * w;
    float FA4[2][8], fa3[2], FA1[8], FA2, fa1i;

    for (int s = 0; s < 2; ++s) {
        if (cw == s) {                 // pair {h=0,h=1} dumps its chunk sig into SB
            if (h == 0) {
                if ((lane & 7) == 0) SB[lane >> 3] = a1i;      // A1[i]
                SB[OFF2 + lane] = A2;
            }
            if (cl < 8) {              // A3 from GEMM tile ct=4 (rows 32h..32h+31)
#pragma unroll
                for (int rt = 0; rt < 2; ++rt)
#pragma unroll
                    for (int reg = 0; reg < 4; ++reg) {
                        const int row = (2*h + rt) * 16 + r0 + reg;
                        SB[OFF3 + (row >> 3) * A3P + (row & 7) * 8 + cl] = acc[rt][4][reg];
                    }
            }
#pragma unroll
            for (int rt = 0; rt < 2; ++rt)
#pragma unroll
                for (int ct = 0; ct < 4; ++ct)
#pragma unroll
                    for (int reg = 0; reg < 4; ++reg)
                        SB[SOFF4 + ((2*h + rt) * 16 + r0 + reg) * P4 + ct * 16 + cl] = acc[rt][ct][reg];
        }
        __syncthreads();
        if (s == 0) {                  // init running sig
            load8(SB, FA1);
            fa1i = SB[i];
            FA2  = SB[OFF2 + lane];
            fa3[0] = SB[OFF3 + i * A3P + j * 8 + k0];
            fa3[1] = SB[OFF3 + i * A3P + j * 8 + k0 + 1];
            load8(SB + SOFF4 + lane * P4 + k0 * 8,       FA4[0]);
            load8(SB + SOFF4 + lane * P4 + (k0 + 1) * 8, FA4[1]);
        } else {                       // running = running (x) SB
            float B1[8]; load8(SB, B1);
            const float b1i = SB[i];
            const float b1j = SB[j];
            const float b2t = SB[OFF2 + lane];
#pragma unroll
            for (int kk = 0; kk < 2; ++kk) {
                const int k = k0 + kk;
                const float b1k  = SB[k];
                const float b3k  = SB[OFF3 + i * A3P + j * 8 + k];
                const float b2jk = SB[OFF2 + j * 8 + k];
                float b4r[8], b2r[8], b3r[8];
                load8(SB + SOFF4 + lane * P4 + k * 8, b4r);
                load8(SB + OFF2 + k * 8,              b2r);
                load8(SB + OFF3 + j * A3P + k * 8,    b3r);
#pragma unroll
                for (int l = 0; l < 8; ++l) {
                    float v = FA4[kk][l] + b4r[l];
                    v = fmaf(fa3[kk], B1[l], v);
                    v = fmaf(FA2,     b2r[l], v);
                    FA4[kk][l] = fmaf(fa1i, b3r[l], v);
                }
                fa3[kk] = fmaf(fa1i, b2jk, fmaf(FA2, b1k, fa3[kk] + b3k));
            }
            FA2 = FA2 + fmaf(fa1i, b1j, b2t);
#pragma unroll
            for (int m = 0; m < 8; ++m) FA1[m] += B1[m];
            fa1i += b1i;
        }
        __syncthreads();
    }

    // ---- write group sig (canonical layout) ----
    float* __restrict__ o = gsigs + (size_t)blockIdx.x * SIGLEN;
    if (w == 0) {
        if (lane < 8) o[lane] = FA1[lane];
        o[OFF2 + lane] = FA2;
    }
    *(float2*)(o + OFF3 + lane * 8 + k0) = make_float2(fa3[0], fa3[1]);
    store8(o + OFF4 + lane * 64 + k0 * 8,       FA4[0]);
    store8(o + OFF4 + lane * 64 + (k0 + 1) * 8, FA4[1]);
}

// ==================== Phase 2: fold the 16 group sigs per batch (r10-proven) ====================
struct BSet {
    float B1[8], b4r[8], b2r[8], b3r[8];
    float b1i, b1j, b2t, b1k, b3k, b2jk;
};

__device__ __forceinline__ void loadB(BSet& S, const float* __restrict__ B,
                                      int lane, int i, int j, int k) {
    load8(B, S.B1);
    S.b1i = B[i];
    S.b1j = B[j];
    S.b2t = B[OFF2 + lane];
    S.b1k = B[k];
    S.b3k = B[OFF3 + lane * 8 + k];
    S.b2jk = B[OFF2 + j * 8 + k];
    load8(B + OFF4 + lane * 64 + k * 8, S.b4r);
    load8(B + OFF2 + k * 8,             S.b2r);
    load8(B + OFF3 + j * 64 + k * 8,    S.b3r);
}

__device__ __forceinline__ void applyB(const BSet& S, float (&A4)[8], float& a3s,
                                       float (&A1)[8], float& A2, float& a1i) {
#pragma unroll
    for (int l = 0; l < 8; ++l) {
        float v = A4[l] + S.b4r[l];
        v = fmaf(a3s, S.B1[l], v);
        v = fmaf(A2,  S.b2r[l], v);
        A4[l] = fmaf(a1i, S.b3r[l], v);
    }
    a3s = fmaf(a1i, S.b2jk, fmaf(A2, S.b1k, a3s + S.b3k));
    A2 = A2 + fmaf(a1i, S.b1j, S.b2t);
#pragma unroll
    for (int m = 0; m < 8; ++m) A1[m] += S.B1[m];
    a1i += S.b1i;
}

template<int NPER>
__global__ __launch_bounds__(512) void sig_combine_kernel(const float* __restrict__ in,
                                                          float* __restrict__ out) {
    const int grp  = blockIdx.x;
    const int tid  = threadIdx.x;
    const int w    = tid >> 6;               // wave id = owned k-row
    const int lane = tid & 63;
    const int i    = lane >> 3;
    const int j    = lane & 7;
    const int k    = w;
    const float* __restrict__ base = in + (size_t)grp * NPER * SIGLEN;

    float A4[8], a3s, A1[8], A2, a1i;
    load8(base, A1);
    a1i = base[i];
    A2  = base[OFF2 + lane];
    a3s = base[OFF3 + lane * 8 + k];
    load8(base + OFF4 + lane * 64 + k * 8, A4);

    BSet Sa, Sb;
    int s = 1;
    loadB(Sa, base + (size_t)s * SIGLEN, lane, i, j, k);
    while (s + 1 < NPER) {
        loadB(Sb, base + (size_t)(s + 1) * SIGLEN, lane, i, j, k);
        applyB(Sa, A4, a3s, A1, A2, a1i);
        ++s;
        if (s + 1 < NPER)
            loadB(Sa, base + (size_t)(s + 1) * SIGLEN, lane, i, j, k);
        applyB(Sb, A4, a3s, A1, A2, a1i);
        ++s;
    }
    if (s < NPER)
        applyB(Sa, A4, a3s, A1, A2, a1i);

    float* __restrict__ o = out + (size_t)grp * SIGLEN;
    if (w == 0) {
        if (lane < 8) o[lane] = A1[lane];
        o[OFF2 + lane] = A2;
    }
    o[OFF3 + lane * 8 + k] = a3s;
    store8(o + OFF4 + lane * 64 + k * 8, A4);
}

extern "C" void kernel_launch(void* const* d_in, const int* in_sizes, int n_in,
                              void* d_out, int out_size, void* d_ws, size_t ws_size,
                              hipStream_t stream) {
    const float* path = (const float*)d_in[0];
    float* out   = (float*)d_out;
    float* gsigs = (float*)d_ws;              // 1024 * 4680 f32 = 19.2 MB

    sig_pair_kernel<<<NBATCH * 16, 256, 0, stream>>>(path, gsigs);
    sig_combine_kernel<16><<<NBATCH, 512, 0, stream>>>(gsigs, out);
}

// Round 23
// 31.293 us; speedup vs baseline: 4.5278x; 1.6043x over previous
//
#include <hip/hip_runtime.h>

#define D8      8
#define LPATH   2048
#define NBATCH  64
#define NSTEPS  2047         // L-1 increments
#define CSTEPS  64           // increments per chunk (last chunk: 63)
#define NCHUNK  32           // chunks per batch
#define SIGLEN  4680         // 8 + 64 + 512 + 4096
#define OFF2    8
#define OFF3    72
#define OFF4    584
#define P4      68           // padded A4 row pitch in LDS sig buffer
#define SIGP    (OFF4 + 64 * P4)
#define ZPITCH  68           // transposed-z row pitch (floats)
#define APITCH  40           // staged row pitch (shorts) = 80 B
#define BROWS   80           // B rows: 64 kl + 8 z-rows + 8 zero-rows

typedef float  f32x4 __attribute__((ext_vector_type(4)));
typedef short  s16x8 __attribute__((ext_vector_type(8)));

__device__ __forceinline__ void load8(const float* __restrict__ p, float* v) {
    float4 a = ((const float4*)p)[0];
    float4 b = ((const float4*)p)[1];
    v[0]=a.x; v[1]=a.y; v[2]=a.z; v[3]=a.w;
    v[4]=b.x; v[5]=b.y; v[6]=b.z; v[7]=b.w;
}
__device__ __forceinline__ void store8(float* __restrict__ p, const float* v) {
    ((float4*)p)[0] = make_float4(v[0],v[1],v[2],v[3]);
    ((float4*)p)[1] = make_float4(v[4],v[5],v[6],v[7]);
}
__device__ __forceinline__ unsigned int f2bf(float f) {   // RNE f32->bf16 bits
    unsigned int u = __builtin_bit_cast(unsigned int, f);
    u += 0x7FFFu + ((u >> 16) & 1u);
    return u >> 16;
}

// pure-register recursion step (no LDS, no A3 loop — A3 moved into the GEMM)
__device__ __forceinline__ void one_step(float Zi, float Zj,
                                         float& A2, float& a1i, float& Wl,
                                         float& c3o, float& c4o, float& h3o, float& h4o) {
    const float p  = Zi * Zj;
    const float uq = a1i * Zj;
    c4o = fmaf(uq, 1.f/6.f, fmaf(p, 1.f/24.f, A2 * 0.5f));
    c3o = fmaf(uq, 0.5f,    fmaf(p, 1.f/6.f,  A2));
    Wl -= Zj;
    h3o = Zi * Wl;
    h4o = p;
    A2 = A2 + fmaf(p, 0.5f, uq);
    a1i += Zi;
}

// ==================== Phase 1: 64-step chunk sigs (MFMA, A3-in-GEMM) + fold-8 ====================
// 256 blocks x 8 waves (all-resident, 1 round). Wave = 1 chunk. LDS ~128 KB/block.
__global__ __launch_bounds__(512) void sig_group_kernel(const float* __restrict__ path,
                                                        float* __restrict__ gsigs) {
    __shared__ __align__(16) float          zt[8][8 * ZPITCH];      // 17.4 KB transposed z
    __shared__ __align__(16) unsigned short Al[8][64 * APITCH];     // 40 KB
    __shared__ __align__(16) unsigned short Bl[8][BROWS * APITCH];  // 51.2 KB
    __shared__ __align__(16) float          SB[SIGP];               // 19.7 KB fold buffer

    const int w    = threadIdx.x >> 6;
    const int lane = threadIdx.x & 63;
    const int G    = blockIdx.x & 3;
    const int b    = blockIdx.x >> 2;
    const int c    = G * 8 + w;                   // chunk within batch
    const int t0   = c * CSTEPS;
    const int t1   = (t0 + CSTEPS < NSTEPS) ? (t0 + CSTEPS) : NSTEPS;
    const int n    = t1 - t0;                     // 64 or 63
    const int i    = lane >> 3;
    const int j    = lane & 7;
    const float* __restrict__ pb = path + (size_t)b * LPATH * D8;

    float* __restrict__ zw = &zt[w][0];
    unsigned short* __restrict__ Aw = &Al[w][0];
    unsigned short* __restrict__ Bw = &Bl[w][0];

    // ---- prologue: transposed z (zt[m][s]) + zero B rows 64..79 ----
    {
        float z8[8];
        if (lane < n) {
            const float* s0 = pb + (size_t)(t0 + lane) * D8;
            float a0[8], a1v[8];
            load8(s0, a0); load8(s0 + D8, a1v);
#pragma unroll
            for (int m = 0; m < 8; ++m) z8[m] = a1v[m] - a0[m];
        } else {
#pragma unroll
            for (int m = 0; m < 8; ++m) z8[m] = 0.f;
        }
#pragma unroll
        for (int m = 0; m < 8; ++m) zw[m * ZPITCH + lane] = z8[m];   // 2-way bank, free

        const uint4 zz = make_uint4(0u, 0u, 0u, 0u);
        *(uint4*)(Bw + 64 * APITCH + lane * 8) = zz;                 // shorts 2560..3071
        if (lane < 16) *(uint4*)(Bw + 64 * APITCH + 512 + lane * 8) = zz;  // 3072..3199
    }

    const float Tj = pb[(size_t)t1 * D8 + j] - pb[(size_t)t0 * D8 + j];

    float A2 = 0.f, a1i = 0.f, Wl = Tj;
    f32x4 acc[4][5];
#pragma unroll
    for (int rt = 0; rt < 4; ++rt)
#pragma unroll
        for (int ct = 0; ct < 5; ++ct)
            acc[rt][ct] = (f32x4){0.f, 0.f, 0.f, 0.f};

    for (int pass = 0; pass < 4; ++pass) {
        const int p16 = pass * 16;
#pragma unroll
        for (int bt = 0; bt < 2; ++bt) {
            const int sb8 = p16 + bt * 8;
            // batched Zi/Zj loads: 4 conflict-free b128 reads cover 8 steps
            f32x4 zia = *(const f32x4*)(zw + i * ZPITCH + sb8);
            f32x4 zib = *(const f32x4*)(zw + i * ZPITCH + sb8 + 4);
            f32x4 zja = *(const f32x4*)(zw + j * ZPITCH + sb8);
            f32x4 zjb = *(const f32x4*)(zw + j * ZPITCH + sb8 + 4);

            unsigned int c3pk[4], c4pk[4], h3pk[4], h4pk[4];
#pragma unroll
            for (int t = 0; t < 4; ++t) {
                const float Zi0 = (2*t   < 4) ? zia[(2*t)   & 3] : zib[(2*t)   & 3];
                const float Zi1 = (2*t+1 < 4) ? zia[(2*t+1) & 3] : zib[(2*t+1) & 3];
                const float Zj0 = (2*t   < 4) ? zja[(2*t)   & 3] : zjb[(2*t)   & 3];
                const float Zj1 = (2*t+1 < 4) ? zja[(2*t+1) & 3] : zjb[(2*t+1) & 3];
                float c3a, c4a, h3a, h4a, c3b, c4b, h3b, h4b;
                one_step(Zi0, Zj0, A2, a1i, Wl, c3a, c4a, h3a, h4a);
                one_step(Zi1, Zj1, A2, a1i, Wl, c3b, c4b, h3b, h4b);
                c3pk[t] = f2bf(c3a) | (f2bf(c3b) << 16);
                c4pk[t] = f2bf(c4a) | (f2bf(c4b) << 16);
                h3pk[t] = f2bf(h3a) | (f2bf(h3b) << 16);
                h4pk[t] = f2bf(h4a) | (f2bf(h4b) << 16);
            }
            *(uint4*)(Aw + lane * APITCH + bt * 8)      = make_uint4(c3pk[0], c3pk[1], c3pk[2], c3pk[3]);
            *(uint4*)(Aw + lane * APITCH + 16 + bt * 8) = make_uint4(c4pk[0], c4pk[1], c4pk[2], c4pk[3]);
            *(uint4*)(Bw + lane * APITCH + bt * 8)      = make_uint4(h3pk[0], h3pk[1], h3pk[2], h3pk[3]);
            *(uint4*)(Bw + lane * APITCH + 16 + bt * 8) = make_uint4(h4pk[0], h4pk[1], h4pk[2], h4pk[3]);
            if (j == 0) {   // z-rows for the A3 output tile (c3 K-half only; c4 half stays 0)
                const unsigned int z0 = f2bf(zia[0]) | (f2bf(zia[1]) << 16);
                const unsigned int z1 = f2bf(zia[2]) | (f2bf(zia[3]) << 16);
                const unsigned int z2 = f2bf(zib[0]) | (f2bf(zib[1]) << 16);
                const unsigned int z3 = f2bf(zib[2]) | (f2bf(zib[3]) << 16);
                *(uint4*)(Bw + (64 + i) * APITCH + bt * 8) = make_uint4(z0, z1, z2, z3);
            }
        }
        // ---- fragments + 20 MFMA ----
        s16x8 af[4], bfr[5];
#pragma unroll
        for (int rt = 0; rt < 4; ++rt)
            af[rt] = *(const s16x8*)(Aw + (rt * 16 + (lane & 15)) * APITCH + (lane >> 4) * 8);
#pragma unroll
        for (int ct = 0; ct < 5; ++ct)
            bfr[ct] = *(const s16x8*)(Bw + (ct * 16 + (lane & 15)) * APITCH + (lane >> 4) * 8);
#pragma unroll
        for (int rt = 0; rt < 4; ++rt)
#pragma unroll
            for (int ct = 0; ct < 5; ++ct)
                acc[rt][ct] = __builtin_amdgcn_mfma_f32_16x16x32_bf16(af[rt], bfr[ct], acc[rt][ct], 0, 0, 0);
    }

    // ==================== in-block fold-8 (Chen, left-to-right) ====================
    const int r0 = (lane >> 4) * 4;    // C/D: row = (lane>>4)*4 + reg, col = lane&15
    const int cl = lane & 15;

    float FA4[8], fa3, FA1[8], FA2, fa1i;

    __syncthreads();
    for (int s = 0; s < 8; ++s) {
        if (w == s) {                  // dump my chunk sig into SB (canonical layout)
            if ((lane & 7) == 0) SB[lane >> 3] = a1i;          // A1[i]
            SB[OFF2 + lane] = A2;
            if (cl < 8) {              // A3 from GEMM tile ct=4: D[row][col=cl]
#pragma unroll
                for (int rt = 0; rt < 4; ++rt)
#pragma unroll
                    for (int reg = 0; reg < 4; ++reg)
                        SB[OFF3 + (rt * 16 + r0 + reg) * 8 + cl] = acc[rt][4][reg];
            }
#pragma unroll
            for (int rt = 0; rt < 4; ++rt)
#pragma unroll
                for (int ct = 0; ct < 4; ++ct)
#pragma unroll
                    for (int reg = 0; reg < 4; ++reg)
                        SB[OFF4 + (rt * 16 + r0 + reg) * P4 + ct * 16 + cl] = acc[rt][ct][reg];
        }
        __syncthreads();
        if (s == 0) {                  // init running sig; wave w owns k-row w
            load8(SB, FA1);
            fa1i = SB[i];
            FA2  = SB[OFF2 + lane];
            fa3  = SB[OFF3 + lane * 8 + w];
            load8(SB + OFF4 + lane * P4 + w * 8, FA4);
        } else {                       // running = running (x) SB
            float B1[8]; load8(SB, B1);
            const float b1i = SB[i];
            const float b1j = SB[j];
            const float b2t = SB[OFF2 + lane];
            const float b1k = SB[w];
            const float b3k = SB[OFF3 + lane * 8 + w];
            const float b2jk = SB[OFF2 + j * 8 + w];
            float b4r[8], b2r[8], b3r[8];
            load8(SB + OFF4 + lane * P4 + w * 8, b4r);
            load8(SB + OFF2 + w * 8,             b2r);
            load8(SB + OFF3 + (j * 8 + w) * 8,   b3r);
#pragma unroll
            for (int l = 0; l < 8; ++l) {
                float v = FA4[l] + b4r[l];
                v = fmaf(fa3,  B1[l], v);
                v = fmaf(FA2,  b2r[l], v);
                FA4[l] = fmaf(fa1i, b3r[l], v);
            }
            fa3 = fmaf(fa1i, b2jk, fmaf(FA2, b1k, fa3 + b3k));
            FA2 = FA2 + fmaf(fa1i, b1j, b2t);
#pragma unroll
            for (int m = 0; m < 8; ++m) FA1[m] += B1[m];
            fa1i += b1i;
        }
        __syncthreads();
    }

    // ---- write group sig (canonical layout) ----
    float* __restrict__ o = gsigs + (size_t)blockIdx.x * SIGLEN;
    if (w == 0) {
        if (lane < 8) o[lane] = FA1[lane];
        o[OFF2 + lane] = FA2;
    }
    o[OFF3 + lane * 8 + w] = fa3;
    store8(o + OFF4 + lane * 64 + w * 8, FA4);
}

// ==================== Phase 2: fold the 4 group sigs per batch ====================
struct BSet {
    float B1[8], b4r[8], b2r[8], b3r[8];
    float b1i, b1j, b2t, b1k, b3k, b2jk;
};

__device__ __forceinline__ void loadB(BSet& S, const float* __restrict__ B,
                                      int lane, int i, int j, int k) {
    load8(B, S.B1);
    S.b1i = B[i];
    S.b1j = B[j];
    S.b2t = B[OFF2 + lane];
    S.b1k = B[k];
    S.b3k = B[OFF3 + lane * 8 + k];
    S.b2jk = B[OFF2 + j * 8 + k];
    load8(B + OFF4 + lane * 64 + k * 8, S.b4r);
    load8(B + OFF2 + k * 8,             S.b2r);
    load8(B + OFF3 + j * 64 + k * 8,    S.b3r);
}

__device__ __forceinline__ void applyB(const BSet& S, float (&A4)[8], float& a3s,
                                       float (&A1)[8], float& A2, float& a1i) {
#pragma unroll
    for (int l = 0; l < 8; ++l) {
        float v = A4[l] + S.b4r[l];
        v = fmaf(a3s, S.B1[l], v);
        v = fmaf(A2,  S.b2r[l], v);
        A4[l] = fmaf(a1i, S.b3r[l], v);
    }
    a3s = fmaf(a1i, S.b2jk, fmaf(A2, S.b1k, a3s + S.b3k));
    A2 = A2 + fmaf(a1i, S.b1j, S.b2t);
#pragma unroll
    for (int m = 0; m < 8; ++m) A1[m] += S.B1[m];
    a1i += S.b1i;
}

template<int NPER>
__global__ __launch_bounds__(512) void sig_combine_kernel(const float* __restrict__ in,
                                                          float* __restrict__ out) {
    const int grp  = blockIdx.x;
    const int tid  = threadIdx.x;
    const int w    = tid >> 6;               // wave id = owned k-row
    const int lane = tid & 63;
    const int i    = lane >> 3;
    const int j    = lane & 7;
    const int k    = w;
    const float* __restrict__ base = in + (size_t)grp * NPER * SIGLEN;

    float A4[8], a3s, A1[8], A2, a1i;
    load8(base, A1);
    a1i = base[i];
    A2  = base[OFF2 + lane];
    a3s = base[OFF3 + lane * 8 + k];
    load8(base + OFF4 + lane * 64 + k * 8, A4);

    BSet Sa, Sb;
    int s = 1;
    loadB(Sa, base + (size_t)s * SIGLEN, lane, i, j, k);
    while (s + 1 < NPER) {
        loadB(Sb, base + (size_t)(s + 1) * SIGLEN, lane, i, j, k);
        applyB(Sa, A4, a3s, A1, A2, a1i);
        ++s;
        if (s + 1 < NPER)
            loadB(Sa, base + (size_t)(s + 1) * SIGLEN, lane, i, j, k);
        applyB(Sb, A4, a3s, A1, A2, a1i);
        ++s;
    }
    if (s < NPER)
        applyB(Sa, A4, a3s, A1, A2, a1i);

    float* __restrict__ o = out + (size_t)grp * SIGLEN;
    if (w == 0) {
        if (lane < 8) o[lane] = A1[lane];
        o[OFF2 + lane] = A2;
    }
    o[OFF3 + lane * 8 + k] = a3s;
    store8(o + OFF4 + lane * 64 + k * 8, A4);
}

extern "C" void kernel_launch(void* const* d_in, const int* in_sizes, int n_in,
                              void* d_out, int out_size, void* d_ws, size_t ws_size,
                              hipStream_t stream) {
    const float* path = (const float*)d_in[0];
    float* out   = (float*)d_out;
    float* gsigs = (float*)d_ws;              // 256 * 4680 f32 = 4.8 MB

    sig_group_kernel<<<NBATCH * 4, 512, 0, stream>>>(path, gsigs);
    sig_combine_kernel<4><<<NBATCH, 512, 0, stream>>>(gsigs, out);
}

// Round 24
// 29.527 us; speedup vs baseline: 4.7986x; 1.0598x over previous
//
#include <hip/hip_runtime.h>
#include <hip/hip_bf16.h>

#define D8      8
#define LPATH   2048
#define NBATCH  64
#define NSTEPS  2047         // L-1 increments
#define CSTEPS  64           // increments per chunk (last chunk: 63)
#define NCHUNK  32           // chunks per batch
#define SIGLEN  4680         // 8 + 64 + 512 + 4096
#define OFF2    8
#define OFF3    72
#define OFF4    584
#define P4      68           // padded A4 row pitch in LDS sig buffer
#define SIGP    (OFF4 + 64 * P4)
#define ZPITCH  68           // transposed-z row pitch (floats)
#define APITCH  40           // staged row pitch (shorts) = 80 B
#define BROWS   80           // B rows: 64 kl + 8 z-rows + 8 zero-rows

typedef float  f32x4 __attribute__((ext_vector_type(4)));
typedef short  s16x8 __attribute__((ext_vector_type(8)));

__device__ __forceinline__ void load8(const float* __restrict__ p, float* v) {
    float4 a = ((const float4*)p)[0];
    float4 b = ((const float4*)p)[1];
    v[0]=a.x; v[1]=a.y; v[2]=a.z; v[3]=a.w;
    v[4]=b.x; v[5]=b.y; v[6]=b.z; v[7]=b.w;
}
__device__ __forceinline__ void store8(float* __restrict__ p, const float* v) {
    ((float4*)p)[0] = make_float4(v[0],v[1],v[2],v[3]);
    ((float4*)p)[1] = make_float4(v[4],v[5],v[6],v[7]);
}
// packed f32->bf16 pair via HW cvt_pk (intrinsic, compiler-scheduled; RNE == f2bf)
__device__ __forceinline__ unsigned int pk2(float lo, float hi) {
    __hip_bfloat162 h2 = __float22bfloat162_rn(make_float2(lo, hi));
    unsigned int r;
    __builtin_memcpy(&r, &h2, 4);
    return r;
}

// pure-register recursion step (no LDS, no A3 loop — A3 moved into the GEMM)
__device__ __forceinline__ void one_step(float Zi, float Zj,
                                         float& A2, float& a1i, float& Wl,
                                         float& c3o, float& c4o, float& h3o, float& h4o) {
    const float p  = Zi * Zj;
    const float uq = a1i * Zj;
    c4o = fmaf(uq, 1.f/6.f, fmaf(p, 1.f/24.f, A2 * 0.5f));
    c3o = fmaf(uq, 0.5f,    fmaf(p, 1.f/6.f,  A2));
    Wl -= Zj;
    h3o = Zi * Wl;
    h4o = p;
    A2 = A2 + fmaf(p, 0.5f, uq);
    a1i += Zi;
}

// ==================== Phase 1: 64-step chunk sigs (MFMA, A3-in-GEMM) + fold-8 ====================
// 256 blocks x 8 waves (all-resident, 1 round). Wave = 1 chunk. LDS ~128 KB/block.
__global__ __launch_bounds__(512) void sig_group_kernel(const float* __restrict__ path,
                                                        float* __restrict__ gsigs) {
    __shared__ __align__(16) float          zt[8][8 * ZPITCH];      // 17.4 KB transposed z
    __shared__ __align__(16) unsigned short Al[8][64 * APITCH];     // 40 KB
    __shared__ __align__(16) unsigned short Bl[8][BROWS * APITCH];  // 51.2 KB
    __shared__ __align__(16) float          SB[SIGP];               // 19.7 KB fold buffer

    const int w    = threadIdx.x >> 6;
    const int lane = threadIdx.x & 63;
    const int G    = blockIdx.x & 3;
    const int b    = blockIdx.x >> 2;
    const int c    = G * 8 + w;                   // chunk within batch
    const int t0   = c * CSTEPS;
    const int t1   = (t0 + CSTEPS < NSTEPS) ? (t0 + CSTEPS) : NSTEPS;
    const int n    = t1 - t0;                     // 64 or 63
    const int i    = lane >> 3;
    const int j    = lane & 7;
    const float* __restrict__ pb = path + (size_t)b * LPATH * D8;

    float* __restrict__ zw = &zt[w][0];
    unsigned short* __restrict__ Aw = &Al[w][0];
    unsigned short* __restrict__ Bw = &Bl[w][0];

    // ---- prologue: transposed z (zt[m][s]) + zero B rows 64..79 ----
    {
        float z8[8];
        if (lane < n) {
            const float* s0 = pb + (size_t)(t0 + lane) * D8;
            float a0[8], a1v[8];
            load8(s0, a0); load8(s0 + D8, a1v);
#pragma unroll
            for (int m = 0; m < 8; ++m) z8[m] = a1v[m] - a0[m];
        } else {
#pragma unroll
            for (int m = 0; m < 8; ++m) z8[m] = 0.f;
        }
#pragma unroll
        for (int m = 0; m < 8; ++m) zw[m * ZPITCH + lane] = z8[m];   // 2-way bank, free

        const uint4 zz = make_uint4(0u, 0u, 0u, 0u);
        *(uint4*)(Bw + 64 * APITCH + lane * 8) = zz;                 // shorts 2560..3071
        if (lane < 16) *(uint4*)(Bw + 64 * APITCH + 512 + lane * 8) = zz;  // 3072..3199
    }

    const float Tj = pb[(size_t)t1 * D8 + j] - pb[(size_t)t0 * D8 + j];

    float A2 = 0.f, a1i = 0.f, Wl = Tj;
    f32x4 acc[4][5];
#pragma unroll
    for (int rt = 0; rt < 4; ++rt)
#pragma unroll
        for (int ct = 0; ct < 5; ++ct)
            acc[rt][ct] = (f32x4){0.f, 0.f, 0.f, 0.f};

    for (int pass = 0; pass < 4; ++pass) {
        const int p16 = pass * 16;
#pragma unroll
        for (int bt = 0; bt < 2; ++bt) {
            const int sb8 = p16 + bt * 8;
            // batched Zi/Zj loads: 4 conflict-free b128 reads cover 8 steps
            f32x4 zia = *(const f32x4*)(zw + i * ZPITCH + sb8);
            f32x4 zib = *(const f32x4*)(zw + i * ZPITCH + sb8 + 4);
            f32x4 zja = *(const f32x4*)(zw + j * ZPITCH + sb8);
            f32x4 zjb = *(const f32x4*)(zw + j * ZPITCH + sb8 + 4);

            unsigned int c3pk[4], c4pk[4], h3pk[4], h4pk[4];
#pragma unroll
            for (int t = 0; t < 4; ++t) {
                const float Zi0 = (2*t   < 4) ? zia[(2*t)   & 3] : zib[(2*t)   & 3];
                const float Zi1 = (2*t+1 < 4) ? zia[(2*t+1) & 3] : zib[(2*t+1) & 3];
                const float Zj0 = (2*t   < 4) ? zja[(2*t)   & 3] : zjb[(2*t)   & 3];
                const float Zj1 = (2*t+1 < 4) ? zja[(2*t+1) & 3] : zjb[(2*t+1) & 3];
                float c3a, c4a, h3a, h4a, c3b, c4b, h3b, h4b;
                one_step(Zi0, Zj0, A2, a1i, Wl, c3a, c4a, h3a, h4a);
                one_step(Zi1, Zj1, A2, a1i, Wl, c3b, c4b, h3b, h4b);
                c3pk[t] = pk2(c3a, c3b);
                c4pk[t] = pk2(c4a, c4b);
                h3pk[t] = pk2(h3a, h3b);
                h4pk[t] = pk2(h4a, h4b);
            }
            *(uint4*)(Aw + lane * APITCH + bt * 8)      = make_uint4(c3pk[0], c3pk[1], c3pk[2], c3pk[3]);
            *(uint4*)(Aw + lane * APITCH + 16 + bt * 8) = make_uint4(c4pk[0], c4pk[1], c4pk[2], c4pk[3]);
            *(uint4*)(Bw + lane * APITCH + bt * 8)      = make_uint4(h3pk[0], h3pk[1], h3pk[2], h3pk[3]);
            *(uint4*)(Bw + lane * APITCH + 16 + bt * 8) = make_uint4(h4pk[0], h4pk[1], h4pk[2], h4pk[3]);
            if (j == 0) {   // z-rows for the A3 output tile (c3 K-half only; c4 half stays 0)
                const unsigned int z0 = pk2(zia[0], zia[1]);
                const unsigned int z1 = pk2(zia[2], zia[3]);
                const unsigned int z2 = pk2(zib[0], zib[1]);
                const unsigned int z3 = pk2(zib[2], zib[3]);
                *(uint4*)(Bw + (64 + i) * APITCH + bt * 8) = make_uint4(z0, z1, z2, z3);
            }
        }
        // ---- fragments + 20 MFMA ----
        s16x8 af[4], bfr[5];
#pragma unroll
        for (int rt = 0; rt < 4; ++rt)
            af[rt] = *(const s16x8*)(Aw + (rt * 16 + (lane & 15)) * APITCH + (lane >> 4) * 8);
#pragma unroll
        for (int ct = 0; ct < 5; ++ct)
            bfr[ct] = *(const s16x8*)(Bw + (ct * 16 + (lane & 15)) * APITCH + (lane >> 4) * 8);
#pragma unroll
        for (int rt = 0; rt < 4; ++rt)
#pragma unroll
            for (int ct = 0; ct < 5; ++ct)
                acc[rt][ct] = __builtin_amdgcn_mfma_f32_16x16x32_bf16(af[rt], bfr[ct], acc[rt][ct], 0, 0, 0);
    }

    // ==================== in-block fold-8 (Chen, left-to-right) ====================
    const int r0 = (lane >> 4) * 4;    // C/D: row = (lane>>4)*4 + reg, col = lane&15
    const int cl = lane & 15;

    float FA4[8], fa3, FA1[8], FA2, fa1i;

    __syncthreads();
    for (int s = 0; s < 8; ++s) {
        if (w == s) {                  // dump my chunk sig into SB (canonical layout)
            if ((lane & 7) == 0) SB[lane >> 3] = a1i;          // A1[i]
            SB[OFF2 + lane] = A2;
            if (cl < 8) {              // A3 from GEMM tile ct=4: D[row][col=cl]
#pragma unroll
                for (int rt = 0; rt < 4; ++rt)
#pragma unroll
                    for (int reg = 0; reg < 4; ++reg)
                        SB[OFF3 + (rt * 16 + r0 + reg) * 8 + cl] = acc[rt][4][reg];
            }
#pragma unroll
            for (int rt = 0; rt < 4; ++rt)
#pragma unroll
                for (int ct = 0; ct < 4; ++ct)
#pragma unroll
                    for (int reg = 0; reg < 4; ++reg)
                        SB[OFF4 + (rt * 16 + r0 + reg) * P4 + ct * 16 + cl] = acc[rt][ct][reg];
        }
        __syncthreads();
        if (s == 0) {                  // init running sig; wave w owns k-row w
            load8(SB, FA1);
            fa1i = SB[i];
            FA2  = SB[OFF2 + lane];
            fa3  = SB[OFF3 + lane * 8 + w];
            load8(SB + OFF4 + lane * P4 + w * 8, FA4);
        } else {                       // running = running (x) SB
            float B1[8]; load8(SB, B1);
            const float b1i = SB[i];
            const float b1j = SB[j];
            const float b2t = SB[OFF2 + lane];
            const float b1k = SB[w];
            const float b3k = SB[OFF3 + lane * 8 + w];
            const float b2jk = SB[OFF2 + j * 8 + w];
            float b4r[8], b2r[8], b3r[8];
            load8(SB + OFF4 + lane * P4 + w * 8, b4r);
            load8(SB + OFF2 + w * 8,             b2r);
            load8(SB + OFF3 + (j * 8 + w) * 8,   b3r);
#pragma unroll
            for (int l = 0; l < 8; ++l) {
                float v = FA4[l] + b4r[l];
                v = fmaf(fa3,  B1[l], v);
                v = fmaf(FA2,  b2r[l], v);
                FA4[l] = fmaf(fa1i, b3r[l], v);
            }
            fa3 = fmaf(fa1i, b2jk, fmaf(FA2, b1k, fa3 + b3k));
            FA2 = FA2 + fmaf(fa1i, b1j, b2t);
#pragma unroll
            for (int m = 0; m < 8; ++m) FA1[m] += B1[m];
            fa1i += b1i;
        }
        __syncthreads();
    }

    // ---- write group sig (canonical layout) ----
    float* __restrict__ o = gsigs + (size_t)blockIdx.x * SIGLEN;
    if (w == 0) {
        if (lane < 8) o[lane] = FA1[lane];
        o[OFF2 + lane] = FA2;
    }
    o[OFF3 + lane * 8 + w] = fa3;
    store8(o + OFF4 + lane * 64 + w * 8, FA4);
}

// ==================== Phase 2: fold the 4 group sigs per batch ====================
struct BSet {
    float B1[8], b4r[8], b2r[8], b3r[8];
    float b1i, b1j, b2t, b1k, b3k, b2jk;
};

__device__ __forceinline__ void loadB(BSet& S, const float* __restrict__ B,
                                      int lane, int i, int j, int k) {
    load8(B, S.B1);
    S.b1i = B[i];
    S.b1j = B[j];
    S.b2t = B[OFF2 + lane];
    S.b1k = B[k];
    S.b3k = B[OFF3 + lane * 8 + k];
    S.b2jk = B[OFF2 + j * 8 + k];
    load8(B + OFF4 + lane * 64 + k * 8, S.b4r);
    load8(B + OFF2 + k * 8,             S.b2r);
    load8(B + OFF3 + j * 64 + k * 8,    S.b3r);
}

__device__ __forceinline__ void applyB(const BSet& S, float (&A4)[8], float& a3s,
                                       float (&A1)[8], float& A2, float& a1i) {
#pragma unroll
    for (int l = 0; l < 8; ++l) {
        float v = A4[l] + S.b4r[l];
        v = fmaf(a3s, S.B1[l], v);
        v = fmaf(A2,  S.b2r[l], v);
        A4[l] = fmaf(a1i, S.b3r[l], v);
    }
    a3s = fmaf(a1i, S.b2jk, fmaf(A2, S.b1k, a3s + S.b3k));
    A2 = A2 + fmaf(a1i, S.b1j, S.b2t);
#pragma unroll
    for (int m = 0; m < 8; ++m) A1[m] += S.B1[m];
    a1i += S.b1i;
}

template<int NPER>
__global__ __launch_bounds__(512) void sig_combine_kernel(const float* __restrict__ in,
                                                          float* __restrict__ out) {
    const int grp  = blockIdx.x;
    const int tid  = threadIdx.x;
    const int w    = tid >> 6;               // wave id = owned k-row
    const int lane = tid & 63;
    const int i    = lane >> 3;
    const int j    = lane & 7;
    const int k    = w;
    const float* __restrict__ base = in + (size_t)grp * NPER * SIGLEN;

    float A4[8], a3s, A1[8], A2, a1i;
    load8(base, A1);
    a1i = base[i];
    A2  = base[OFF2 + lane];
    a3s = base[OFF3 + lane * 8 + k];
    load8(base + OFF4 + lane * 64 + k * 8, A4);

    BSet Sa, Sb;
    int s = 1;
    loadB(Sa, base + (size_t)s * SIGLEN, lane, i, j, k);
    while (s + 1 < NPER) {
        loadB(Sb, base + (size_t)(s + 1) * SIGLEN, lane, i, j, k);
        applyB(Sa, A4, a3s, A1, A2, a1i);
        ++s;
        if (s + 1 < NPER)
            loadB(Sa, base + (size_t)(s + 1) * SIGLEN, lane, i, j, k);
        applyB(Sb, A4, a3s, A1, A2, a1i);
        ++s;
    }
    if (s < NPER)
        applyB(Sa, A4, a3s, A1, A2, a1i);

    float* __restrict__ o = out + (size_t)grp * SIGLEN;
    if (w == 0) {
        if (lane < 8) o[lane] = A1[lane];
        o[OFF2 + lane] = A2;
    }
    o[OFF3 + lane * 8 + k] = a3s;
    store8(o + OFF4 + lane * 64 + k * 8, A4);
}

extern "C" void kernel_launch(void* const* d_in, const int* in_sizes, int n_in,
                              void* d_out, int out_size, void* d_ws, size_t ws_size,
                              hipStream_t stream) {
    const float* path = (const float*)d_in[0];
    float* out   = (float*)d_out;
    float* gsigs = (float*)d_ws;              // 256 * 4680 f32 = 4.8 MB

    sig_group_kernel<<<NBATCH * 4, 512, 0, stream>>>(path, gsigs);
    sig_combine_kernel<4><<<NBATCH, 512, 0, stream>>>(gsigs, out);
}